// Round 14
// baseline (934.274 us; speedup 1.0000x reference)
//
#include <hip/hip_runtime.h>
#include <hip/hip_bf16.h>
#include <math.h>

// ---------------------------------------------------------------------------
// Linear_Transformer on MI355X (gfx950). fp32 I/O, bf16 MFMA internals,
// fp32 residual stream.
// Round 14: LDS-staged epilogue for gemm_bt256 (FF1). Round-13 showed the
// 256-tile's MFMA gain is eaten by stores: nt-outer = 317MB WRITE (2.4x
// amplification, ~65us), nt-inner = store-pipe stalls (round 12). Staging
// the C-tile through freed As0/As1 LDS (4 passes of 32 rows/wave) and
// storing row-major dwordx4 (8 lanes = one full 128B line) gets clean AND
// unstalled stores. Everything else byte-identical to round 13.
// ---------------------------------------------------------------------------

typedef __hip_bfloat16 bf16;
typedef __attribute__((ext_vector_type(8))) short short8;   // 8 bf16 (MFMA A/B frag)
typedef __attribute__((ext_vector_type(4))) float floatx4;  // MFMA C/D frag

#define SEQ   4096
#define NBAT  8
#define DM    512
#define DINP  128
#define DFF   2048
#define NREAL 3000
#define CS    40              // ctx_mfma LDS stride (80B, 16B-aligned)

#define MFMA16(a,b,c) __builtin_amdgcn_mfma_f32_16x16x32_bf16((a),(b),(c),0,0,0)

// async global->LDS, 16B per lane, deposits at lds + lane*16
__device__ __forceinline__ void gload_lds16(const void* g, void* l) {
  auto* gp = reinterpret_cast<const __attribute__((address_space(1))) unsigned int*>(
      reinterpret_cast<uintptr_t>(g));
  auto* lp = reinterpret_cast<__attribute__((address_space(3))) unsigned int*>(
      reinterpret_cast<uintptr_t>(l));
  __builtin_amdgcn_global_load_lds(gp, lp, 16, 0, 0);
}

// ---------------------------------------------------------------------------
__global__ __launch_bounds__(256) void beacon(float* __restrict__ out, long n) {
  long i = (long)blockIdx.x * 256 + threadIdx.x;
  if (i < n) out[i] = 10000.f;
}

// ---------------------------------------------------------------------------
// All 8 weight transposes in one launch. Wt[n][k] = n<N ? (bf16)W[k][n] : 0
// ---------------------------------------------------------------------------
__global__ __launch_bounds__(256) void transpose8(
    const float* __restrict__ W1, const float* __restrict__ Wq,
    const float* __restrict__ Wk, const float* __restrict__ Wv,
    const float* __restrict__ Wo, const float* __restrict__ Wf1,
    const float* __restrict__ Wf2, const float* __restrict__ W2,
    bf16* __restrict__ wt) {
  const int Ks[8]   = {128, 512, 512, 512, 512, 512, 2048, 512};
  const int Ns[8]   = {512, 512, 512, 512, 512, 2048, 512, 64};
  const int Nps[8]  = {512, 512, 512, 512, 512, 2048, 512, 128};
  const long Ofs[8] = {0L, 65536L, 327680L, 589824L, 851968L, 1114112L, 2162688L, 3211264L};
  int zi = blockIdx.z;
  int K = Ks[zi], N = Ns[zi], Npad = Nps[zi];
  int k0 = blockIdx.x * 64, n0 = blockIdx.y * 64;
  if (k0 >= K || n0 >= Npad) return;
  const float* W = zi == 0 ? W1 : zi == 1 ? Wq : zi == 2 ? Wk : zi == 3 ? Wv
                 : zi == 4 ? Wo : zi == 5 ? Wf1 : zi == 6 ? Wf2 : W2;
  bf16* Wt = wt + Ofs[zi];
  __shared__ float t[64][65];
  int r = threadIdx.x >> 2, c = (threadIdx.x & 3) * 16;
#pragma unroll
  for (int i = 0; i < 16; i++) {
    int n = n0 + c + i;
    t[r][c + i] = (n < N) ? W[(long)(k0 + r) * N + n] : 0.f;
  }
  __syncthreads();
#pragma unroll
  for (int i = 0; i < 16; i++)
    Wt[(long)(n0 + r) * K + k0 + c + i] = (bf16)t[c + i][r];
}

// ---------------------------------------------------------------------------
__device__ inline uint4 pack8(const float* p) {
  union { bf16 h[8]; uint4 u; } r;
  float4 a = *(const float4*)p;
  float4 b = *(const float4*)(p + 4);
  r.h[0] = (bf16)a.x; r.h[1] = (bf16)a.y; r.h[2] = (bf16)a.z; r.h[3] = (bf16)a.w;
  r.h[4] = (bf16)b.x; r.h[5] = (bf16)b.y; r.h[6] = (bf16)b.z; r.h[7] = (bf16)b.w;
  return r.u;
}

// ---------------------------------------------------------------------------
// 256x128-tile MFMA GEMM (FF1): acc[8][4], BK=64 twin halves.
// EPI: 1 bf16->Cb, 4 gelu->Cb (both via LDS-staged coalesced stores),
//      2 Cf+= (scalar fallback). launch_bounds(256,2).
// ---------------------------------------------------------------------------
__global__ __launch_bounds__(256, 2) void gemm_bt256(
    const bf16* __restrict__ A, const bf16* __restrict__ Bt,
    const float* __restrict__ bias, float* __restrict__ Cf, bf16* __restrict__ Cb,
    int K, int lda, int ldb, int ldc, int EPI,
    long aBatch, long bBatch, int zdiv, long cOuter, long cInner) {
  __shared__ __align__(16) bf16 As0[256 * 32];
  __shared__ __align__(16) bf16 As1[256 * 32];
  __shared__ __align__(16) bf16 Bs0[128 * 32];
  __shared__ __align__(16) bf16 Bs1[128 * 32];
  const int tid = threadIdx.x;
  const int bz = blockIdx.z;
  A += (long)bz * aBatch;
  Bt += (long)bz * bBatch;
  const long cOff = (long)(bz / zdiv) * cOuter + (long)(bz % zdiv) * cInner;
  const int row0 = blockIdx.y * 256;
  const int col0 = blockIdx.x * 128;
  const int lane = tid & 63, wid = tid >> 6;
  const int wm = (wid & 1) * 128, wn = (wid >> 1) * 64;
  const int lr = lane & 15, lk = (lane >> 4) * 8, q4 = lane >> 4;

  floatx4 acc[8][4];
#pragma unroll
  for (int i = 0; i < 8; i++)
#pragma unroll
    for (int j = 0; j < 4; j++) acc[i][j] = {0.f, 0.f, 0.f, 0.f};

  const bf16* pAa = A + (long)(row0 + wid * 64 + (lane >> 2)) * lda + (lane & 3) * 8;
  const bf16* pBa = Bt + (long)(col0 + wid * 32 + (lane >> 2)) * ldb + (lane & 3) * 8;
  for (int k0 = 0; k0 < K; k0 += 64) {
    __syncthreads();
#pragma unroll
    for (int i = 0; i < 4; i++) {
      gload_lds16(pAa + (long)i * 16 * lda, &As0[(wid * 64 + i * 16) * 32]);
      gload_lds16(pAa + (long)i * 16 * lda + 32, &As1[(wid * 64 + i * 16) * 32]);
    }
#pragma unroll
    for (int i = 0; i < 2; i++) {
      gload_lds16(pBa + (long)i * 16 * ldb, &Bs0[(wid * 32 + i * 16) * 32]);
      gload_lds16(pBa + (long)i * 16 * ldb + 32, &Bs1[(wid * 32 + i * 16) * 32]);
    }
    pAa += 64; pBa += 64;
    __syncthreads();
    {
      short8 af[8], bfr[4];
#pragma unroll
      for (int mt = 0; mt < 8; mt++) af[mt] = *(const short8*)(&As0[(wm + mt * 16 + lr) * 32 + lk]);
#pragma unroll
      for (int nt = 0; nt < 4; nt++) bfr[nt] = *(const short8*)(&Bs0[(wn + nt * 16 + lr) * 32 + lk]);
#pragma unroll
      for (int mt = 0; mt < 8; mt++)
#pragma unroll
        for (int nt = 0; nt < 4; nt++)
          acc[mt][nt] = MFMA16(af[mt], bfr[nt], acc[mt][nt]);
#pragma unroll
      for (int mt = 0; mt < 8; mt++) af[mt] = *(const short8*)(&As1[(wm + mt * 16 + lr) * 32 + lk]);
#pragma unroll
      for (int nt = 0; nt < 4; nt++) bfr[nt] = *(const short8*)(&Bs1[(wn + nt * 16 + lr) * 32 + lk]);
#pragma unroll
      for (int mt = 0; mt < 8; mt++)
#pragma unroll
        for (int nt = 0; nt < 4; nt++)
          acc[mt][nt] = MFMA16(af[mt], bfr[nt], acc[mt][nt]);
    }
  }

  if (EPI == 2) {
    // scalar fallback (unused by FF1)
#pragma unroll
    for (int nt = 0; nt < 4; nt++) {
      int c = col0 + wn + nt * 16 + lr;
      float bv = bias ? bias[c] : 0.f;
#pragma unroll
      for (int mt = 0; mt < 8; mt++) {
        long rb = row0 + wm + mt * 16 + q4 * 4;
#pragma unroll
        for (int reg = 0; reg < 4; reg++)
          Cf[cOff + (rb + reg) * (long)ldc + c] += acc[mt][nt][reg] + bv;
      }
    }
    return;
  }

  // ---- LDS-staged coalesced epilogue (EPI 1 / 4) ----
  __syncthreads();  // all waves done with As0/As1 (K-loop reads complete)
  // per-wave 2304-element (4.5KB) stage region inside freed As0/As1
  bf16* stg = (wid < 2 ? As0 : As1) + (wid & 1) * 2304;
  float bv[4];
#pragma unroll
  for (int nt = 0; nt < 4; nt++) bv[nt] = bias ? bias[col0 + wn + nt * 16 + lr] : 0.f;
#pragma unroll
  for (int p = 0; p < 4; p++) {           // 32 rows per pass
#pragma unroll
    for (int mt2 = 0; mt2 < 2; mt2++) {
      int mt = p * 2 + mt2;
#pragma unroll
      for (int nt = 0; nt < 4; nt++) {
#pragma unroll
        for (int reg = 0; reg < 4; reg++) {
          float v = acc[mt][nt][reg] + bv[nt];
          if (EPI == 4) v = 0.5f * v * (1.f + erff(v * 0.70710678118654752f));
          stg[(mt2 * 16 + q4 * 4 + reg) * 72 + nt * 16 + lr] = (bf16)v;
        }
      }
    }
    // read back row-major, store full 128B lines (8 lanes x 16B per row)
    int rl = lane >> 3, cb = (lane & 7) * 8;
#pragma unroll
    for (int i = 0; i < 4; i++) {
      int r = i * 8 + rl;
      uint4 d = *(const uint4*)(&stg[r * 72 + cb]);
      long grow = row0 + wm + p * 32 + r;
      *(uint4*)(&Cb[cOff + grow * (long)ldc + col0 + wn + cb]) = d;
    }
  }
}

// ---------------------------------------------------------------------------
// Generic MFMA GEMM (round-10, known good): 128x128 tile.
// AMODE 0: bf16 A async BK=64 twin halves. AMODE 1: fp32 x w/ zero pad rows.
// AMODE 2: fp32 A. EPI: 0 tanh->Cf 1 bf16->Cb 2 Cf+= 4 gelu->Cb 5 remap->Cf
// ---------------------------------------------------------------------------
__global__ __launch_bounds__(256) void gemm_bt(
    const void* __restrict__ Avoid, const bf16* __restrict__ Bt,
    const float* __restrict__ bias, float* __restrict__ Cf, bf16* __restrict__ Cb,
    int K, int lda, int ldb, int ldc, int EPI, int AMODE,
    long aBatch, long bBatch, int zdiv, long cOuter, long cInner) {
  __shared__ __align__(16) bf16 As0[128 * 32];
  __shared__ __align__(16) bf16 As1[128 * 32];
  __shared__ __align__(16) bf16 Bs0[128 * 32];
  __shared__ __align__(16) bf16 Bs1[128 * 32];
  const int tid = threadIdx.x;
  const int bz = blockIdx.z;
  Bt += (long)bz * bBatch;
  const long cOff = (long)(bz / zdiv) * cOuter + (long)(bz % zdiv) * cInner;
  const int row0 = blockIdx.y * 128;
  const int col0 = blockIdx.x * 128;
  const int lane = tid & 63, wid = tid >> 6;
  const int wm = (wid & 1) * 64, wn = (wid >> 1) * 64;
  const int lr = lane & 15, lk = (lane >> 4) * 8;

  floatx4 acc[4][4];
#pragma unroll
  for (int i = 0; i < 4; i++)
#pragma unroll
    for (int j = 0; j < 4; j++) acc[i][j] = {0.f, 0.f, 0.f, 0.f};

  if (AMODE == 0) {
    const bf16* A = (const bf16*)Avoid + (long)bz * aBatch;
    const bf16* pAa = A + (long)(row0 + wid * 16 + (lane >> 2)) * lda + (lane & 3) * 8;
    const bf16* pBa = Bt + (long)(col0 + wid * 16 + (lane >> 2)) * ldb + (lane & 3) * 8;
    bf16* ldsA0 = &As0[wid * 16 * 32];
    bf16* ldsA1 = &As1[wid * 16 * 32];
    bf16* ldsB0 = &Bs0[wid * 16 * 32];
    bf16* ldsB1 = &Bs1[wid * 16 * 32];
    const long a64 = (long)64 * lda, b64 = (long)64 * ldb;
    for (int k0 = 0; k0 < K; k0 += 64) {
      __syncthreads();
      gload_lds16(pAa, ldsA0);
      gload_lds16(pAa + a64, ldsA0 + 64 * 32);
      gload_lds16(pAa + 32, ldsA1);
      gload_lds16(pAa + a64 + 32, ldsA1 + 64 * 32);
      gload_lds16(pBa, ldsB0);
      gload_lds16(pBa + b64, ldsB0 + 64 * 32);
      gload_lds16(pBa + 32, ldsB1);
      gload_lds16(pBa + b64 + 32, ldsB1 + 64 * 32);
      pAa += 64; pBa += 64;
      __syncthreads();
      short8 af[4], bfr[4];
#pragma unroll
      for (int mt = 0; mt < 4; mt++) af[mt] = *(const short8*)(&As0[(wm + mt * 16 + lr) * 32 + lk]);
#pragma unroll
      for (int nt = 0; nt < 4; nt++) bfr[nt] = *(const short8*)(&Bs0[(wn + nt * 16 + lr) * 32 + lk]);
#pragma unroll
      for (int mt = 0; mt < 4; mt++)
#pragma unroll
        for (int nt = 0; nt < 4; nt++)
          acc[mt][nt] = MFMA16(af[mt], bfr[nt], acc[mt][nt]);
#pragma unroll
      for (int mt = 0; mt < 4; mt++) af[mt] = *(const short8*)(&As1[(wm + mt * 16 + lr) * 32 + lk]);
#pragma unroll
      for (int nt = 0; nt < 4; nt++) bfr[nt] = *(const short8*)(&Bs1[(wn + nt * 16 + lr) * 32 + lk]);
#pragma unroll
      for (int mt = 0; mt < 4; mt++)
#pragma unroll
        for (int nt = 0; nt < 4; nt++)
          acc[mt][nt] = MFMA16(af[mt], bfr[nt], acc[mt][nt]);
    }
  } else {
    const float* Af = (const float*)Avoid;
    const int srow = tid >> 2;
    const int skcol = (tid & 3) * 8;
    const long r0 = row0 + srow, r1 = r0 + 64;
    const bf16* pB = Bt + (long)(col0 + srow) * ldb + skcol;
    const int ldsOff = srow * 32 + skcol;
    const float* pF0; const float* pF1;
    bool v0 = true, v1 = true;
    if (AMODE == 1) {
      int t0 = (int)(r0 & (SEQ - 1)), t1 = (int)(r1 & (SEQ - 1));
      v0 = t0 < NREAL; v1 = t1 < NREAL;
      if (!v0) t0 = 0;
      if (!v1) t1 = 0;
      pF0 = Af + ((r0 >> 12) * NREAL + t0) * DINP + skcol;
      pF1 = Af + ((r1 >> 12) * NREAL + t1) * DINP + skcol;
    } else {
      pF0 = Af + r0 * lda + skcol;
      pF1 = Af + r1 * lda + skcol;
    }
    for (int k0 = 0; k0 < K; k0 += 32) {
      uint4 b0 = *(const uint4*)(pB);
      uint4 b1 = *(const uint4*)(pB + (long)64 * ldb);
      pB += 32;
      uint4 a0 = {0, 0, 0, 0}, a1 = {0, 0, 0, 0};
      if (v0) a0 = pack8(pF0);
      if (v1) a1 = pack8(pF1);
      pF0 += 32; pF1 += 32;
      __syncthreads();
      *(uint4*)(&As0[ldsOff]) = a0;
      *(uint4*)(&As0[ldsOff + 64 * 32]) = a1;
      *(uint4*)(&Bs0[ldsOff]) = b0;
      *(uint4*)(&Bs0[ldsOff + 64 * 32]) = b1;
      __syncthreads();
      short8 af[4], bfr[4];
#pragma unroll
      for (int mt = 0; mt < 4; mt++) af[mt] = *(const short8*)(&As0[(wm + mt * 16 + lr) * 32 + lk]);
#pragma unroll
      for (int nt = 0; nt < 4; nt++) bfr[nt] = *(const short8*)(&Bs0[(wn + nt * 16 + lr) * 32 + lk]);
#pragma unroll
      for (int mt = 0; mt < 4; mt++)
#pragma unroll
        for (int nt = 0; nt < 4; nt++)
          acc[mt][nt] = MFMA16(af[mt], bfr[nt], acc[mt][nt]);
    }
  }

#pragma unroll
  for (int nt = 0; nt < 4; nt++) {
    int c = col0 + wn + nt * 16 + lr;
    float bv = 0.f;
    if (bias) {
      if (EPI == 5) { if (c < 64) bv = bias[c]; }
      else bv = bias[c];
    }
#pragma unroll
    for (int mt = 0; mt < 4; mt++) {
      long rb = row0 + wm + mt * 16 + (lane >> 4) * 4;
#pragma unroll
      for (int reg = 0; reg < 4; reg++) {
        float v = acc[mt][nt][reg] + bv;
        long ri = rb + reg;
        long idx = cOff + ri * (long)ldc + c;
        if (EPI == 0) Cf[idx] = tanhf(v);
        else if (EPI == 1) Cb[idx] = (bf16)v;
        else if (EPI == 2) Cf[idx] += v;
        else if (EPI == 4) { float g = 0.5f * v * (1.f + erff(v * 0.70710678118654752f)); Cb[idx] = (bf16)g; }
        else if (EPI == 5) {
          int bb = (int)(ri >> 12); int tt = (int)(ri & (SEQ - 1));
          if (tt < NREAL && c < 64) Cf[((long)bb * NREAL + tt) * 64 + c] = v;
        }
      }
    }
  }
}

// ---------------------------------------------------------------------------
// LayerNorm over 512 fp32 -> bf16. One wave per row, 4 rows per block.
// ---------------------------------------------------------------------------
__global__ __launch_bounds__(256) void ln_kernel(const float* __restrict__ h,
                                                 const float* __restrict__ g,
                                                 const float* __restrict__ bta,
                                                 bf16* __restrict__ out) {
  int wid = threadIdx.x >> 6, lane = threadIdx.x & 63;
  long row = (long)blockIdx.x * 4 + wid;
  const float* src = h + row * DM + lane * 8;
  float4 a = *(const float4*)(src);
  float4 b = *(const float4*)(src + 4);
  float x[8] = {a.x, a.y, a.z, a.w, b.x, b.y, b.z, b.w};
  float s = 0.f, sq = 0.f;
#pragma unroll
  for (int i = 0; i < 8; i++) { s += x[i]; sq += x[i] * x[i]; }
#pragma unroll
  for (int m = 32; m >= 1; m >>= 1) { s += __shfl_xor(s, m, 64); sq += __shfl_xor(sq, m, 64); }
  float mu = s * (1.f / DM);
  float var = sq * (1.f / DM) - mu * mu;
  float rstd = rsqrtf(var + 1e-5f);
  const float* gp = g + lane * 8;
  const float* bp = bta + lane * 8;
  bf16* dst = out + row * DM + lane * 8;
#pragma unroll
  for (int i = 0; i < 8; i++)
    dst[i] = (bf16)((x[i] - mu) * rstd * gp[i] + bp[i]);
}

// ---------------------------------------------------------------------------
// Local attention, head 0. Grid (2 halves, 32 windows, GB batches).
// ---------------------------------------------------------------------------
__global__ __launch_bounds__(256) void local_attn(const bf16* __restrict__ q,
                                                  const bf16* __restrict__ k,
                                                  const bf16* __restrict__ v,
                                                  bf16* __restrict__ att) {
  int half = blockIdx.x, w = blockIdx.y, b = blockIdx.z;
  int tid = threadIdx.x, wid = tid >> 6, lane = tid & 63;
  int lr = lane & 15, lq4 = lane >> 4;
  __shared__ __align__(16) bf16 Ks[32 * 128];   // [j][d]
  __shared__ __align__(16) bf16 Vts[128 * 32];  // [d][j]
  __shared__ __align__(16) bf16 Ps[4][16 * 32]; // per-wave P scratch

  int t0 = w * 128 + half * 64 + wid * 16;
  long qbase = ((long)b * SEQ + t0 + lr) * DM;
  short8 qf[4];
#pragma unroll
  for (int ks = 0; ks < 4; ks++) qf[ks] = *(const short8*)(q + qbase + ks * 32 + lq4 * 8);

  floatx4 Oacc[8];
#pragma unroll
  for (int i = 0; i < 8; i++) Oacc[i] = {0.f, 0.f, 0.f, 0.f};
  float rs[4] = {0.f, 0.f, 0.f, 0.f};

  int keystart = w * 128 - 128;
  for (int ch = 0; ch < 12; ch++) {
    int kb = keystart + ch * 32;
    if (kb < 0 || kb >= SEQ) continue;  // uniform per block
    {
      int j = tid >> 3, d = (tid & 7) * 16;
      const bf16* ksrc = k + ((long)b * SEQ + kb + j) * DM + d;
      *(uint4*)(&Ks[j * 128 + d]) = *(const uint4*)(ksrc);
      *(uint4*)(&Ks[j * 128 + d + 8]) = *(const uint4*)(ksrc + 8);
      const bf16* vsrc = v + ((long)b * SEQ + kb + j) * DM + d;
#pragma unroll
      for (int e = 0; e < 16; e++) Vts[(d + e) * 32 + j] = vsrc[e];
    }
    __syncthreads();
    floatx4 s0 = {0.f, 0.f, 0.f, 0.f}, s1 = {0.f, 0.f, 0.f, 0.f};
#pragma unroll
    for (int ks = 0; ks < 4; ks++) {
      short8 kf0 = *(const short8*)(&Ks[(0 + lr) * 128 + ks * 32 + lq4 * 8]);
      short8 kf1 = *(const short8*)(&Ks[(16 + lr) * 128 + ks * 32 + lq4 * 8]);
      s0 = MFMA16(qf[ks], kf0, s0);
      s1 = MFMA16(qf[ks], kf1, s1);
    }
#pragma unroll
    for (int reg = 0; reg < 4; reg++) {
      float e0 = __expf(s0[reg] * 0.08838834764831845f);
      float e1 = __expf(s1[reg] * 0.08838834764831845f);
      rs[reg] += e0 + e1;
      Ps[wid][(lq4 * 4 + reg) * 32 + lr] = (bf16)e0;
      Ps[wid][(lq4 * 4 + reg) * 32 + 16 + lr] = (bf16)e1;
    }
    __syncthreads();
    short8 pf = *(const short8*)(&Ps[wid][lr * 32 + lq4 * 8]);
#pragma unroll
    for (int nt = 0; nt < 8; nt++) {
      short8 vf = *(const short8*)(&Vts[(nt * 16 + lr) * 32 + lq4 * 8]);
      Oacc[nt] = MFMA16(pf, vf, Oacc[nt]);
    }
    __syncthreads();
  }
#pragma unroll
  for (int m = 1; m < 16; m <<= 1)
#pragma unroll
    for (int reg = 0; reg < 4; reg++) rs[reg] += __shfl_xor(rs[reg], m, 64);
  long obase = ((long)b * SEQ + t0 + lq4 * 4) * DM;
#pragma unroll
  for (int nt = 0; nt < 8; nt++)
#pragma unroll
    for (int reg = 0; reg < 4; reg++)
      att[obase + (long)reg * DM + nt * 16 + lr] = (bf16)(Oacc[nt][reg] / rs[reg]);
}

// ---------------------------------------------------------------------------
// Linear-attn q-softmax: qp[z][t][128] = softmax(q_head)*d^-0.5, z=lb*3+h2
// ---------------------------------------------------------------------------
__global__ __launch_bounds__(256) void qp_softmax(const bf16* __restrict__ q, bf16* __restrict__ qp) {
  int wid = threadIdx.x >> 6, lane = threadIdx.x & 63;
  long task = (long)blockIdx.x * 4 + wid;
  int tt = (int)(task & (SEQ - 1));
  int z6 = (int)(task >> 12);
  int lb = z6 / 3, h2 = z6 % 3;
  const bf16* src = q + ((long)lb * SEQ + tt) * DM + (h2 + 1) * 128 + lane * 2;
  float x0 = (float)src[0], x1 = (float)src[1];
  float m = fmaxf(x0, x1);
#pragma unroll
  for (int s = 32; s >= 1; s >>= 1) m = fmaxf(m, __shfl_xor(m, s, 64));
  float e0 = __expf(x0 - m), e1 = __expf(x1 - m);
  float sm = e0 + e1;
#pragma unroll
  for (int s = 32; s >= 1; s >>= 1) sm += __shfl_xor(sm, s, 64);
  float inv = 0.08838834764831845f / sm;
  bf16* dst = qp + task * 128 + lane * 2;
  dst[0] = (bf16)(e0 * inv);
  dst[1] = (bf16)(e1 * inv);
}

// ---------------------------------------------------------------------------
// k column stats, phase 1: per-(z, 128-row chunk) column max and exp-sum.
// ---------------------------------------------------------------------------
__global__ __launch_bounds__(128) void kstats_part(const bf16* __restrict__ k,
                                                   float* __restrict__ part, int lOff) {
  int chunk = blockIdx.x, z = blockIdx.y;
  int lb = z / 3, h2 = z % 3, ch = (h2 + 1) * 128;
  int d = threadIdx.x;
  const bf16* base = k + ((long)lb * SEQ + chunk * 128) * DM + ch + d;
  float m = -1e30f;
#pragma unroll 4
  for (int t = 0; t < 128; t++) m = fmaxf(m, (float)base[(long)t * DM]);
  float l = 0.f;
#pragma unroll 4
  for (int t = 0; t < 128; t++) l += __expf((float)base[(long)t * DM] - m);
  int idx = (z * 32 + chunk) * 128 + d;
  part[idx] = m;
  part[lOff + idx] = l;
}

// phase 2: combine 32 chunk stats -> kml[z*256+d]=M, +128=L
__global__ __launch_bounds__(128) void kstats_comb(const float* __restrict__ part,
                                                   float* __restrict__ kml, int lOff) {
  int z = blockIdx.x, d = threadIdx.x;
  float M = -1e30f;
#pragma unroll 4
  for (int c = 0; c < 32; c++) M = fmaxf(M, part[(z * 32 + c) * 128 + d]);
  float L = 0.f;
#pragma unroll 4
  for (int c = 0; c < 32; c++) {
    int i = (z * 32 + c) * 128 + d;
    L += part[lOff + i] * __expf(part[i] - M);
  }
  kml[z * 256 + d] = M;
  kml[z * 256 + 128 + d] = L;
}

// ---------------------------------------------------------------------------
// ctx via MFMA: part[z][chunk][e*128+d] = sum_{t in 512-chunk} v[t][e]*k'[t][d]
// ---------------------------------------------------------------------------
__global__ __launch_bounds__(256) void ctx_mfma(const bf16* __restrict__ k,
                                                const bf16* __restrict__ v,
                                                const float* __restrict__ kml,
                                                float* __restrict__ part) {
  int chunk = blockIdx.x, z = blockIdx.y;
  int lb = z / 3, h2 = z % 3, ch = (h2 + 1) * 128;
  int tid = threadIdx.x, lane = tid & 63, wid = tid >> 6;
  const int wm = (wid & 1) * 64, wn = (wid >> 1) * 64;
  const int lr = lane & 15, lk = (lane >> 4) * 8;
  __shared__ float ml2[128];
  __shared__ __align__(16) bf16 Vt[128 * CS];
  __shared__ __align__(16) bf16 Kt[128 * CS];
  if (tid < 128)
    ml2[tid] = kml[z * 256 + tid] + logf(kml[z * 256 + 128 + tid]);

  int j = tid >> 3, d0 = (tid & 7) * 16;
  const bf16* vsrc = v + ((long)lb * SEQ + chunk * 512 + j) * DM + ch + d0;
  const bf16* ksrc = k + ((long)lb * SEQ + chunk * 512 + j) * DM + ch + d0;

  floatx4 acc[4][4];
#pragma unroll
  for (int i = 0; i < 4; i++)
#pragma unroll
    for (int jj = 0; jj < 4; jj++) acc[i][jj] = {0.f, 0.f, 0.f, 0.f};

  for (int s = 0; s < 16; s++) {
    union { bf16 h[16]; uint4 u[2]; } va, ka;
    va.u[0] = *(const uint4*)(vsrc); va.u[1] = *(const uint4*)(vsrc + 8);
    ka.u[0] = *(const uint4*)(ksrc); ka.u[1] = *(const uint4*)(ksrc + 8);
    vsrc += (long)32 * DM; ksrc += (long)32 * DM;
    __syncthreads();
#pragma unroll
    for (int e = 0; e < 16; e++) {
      Vt[(d0 + e) * CS + j] = va.h[e];
      Kt[(d0 + e) * CS + j] = (bf16)__expf((float)ka.h[e] - ml2[d0 + e]);
    }
    __syncthreads();
    short8 af[4], bfr[4];
#pragma unroll
    for (int mt = 0; mt < 4; mt++) af[mt] = *(const short8*)(&Vt[(wm + mt * 16 + lr) * CS + lk]);
#pragma unroll
    for (int nt = 0; nt < 4; nt++) bfr[nt] = *(const short8*)(&Kt[(wn + nt * 16 + lr) * CS + lk]);
#pragma unroll
    for (int mt = 0; mt < 4; mt++)
#pragma unroll
      for (int nt = 0; nt < 4; nt++)
        acc[mt][nt] = MFMA16(af[mt], bfr[nt], acc[mt][nt]);
  }

  float* dst = part + ((long)z * 8 + chunk) * 16384;
#pragma unroll
  for (int nt = 0; nt < 4; nt++) {
    int c = wn + nt * 16 + lr;
#pragma unroll
    for (int mt = 0; mt < 4; mt++) {
      int rb = wm + mt * 16 + (lane >> 4) * 4;
#pragma unroll
      for (int reg = 0; reg < 4; reg++)
        dst[(rb + reg) * 128 + c] = acc[mt][nt][reg];
    }
  }
}

__global__ __launch_bounds__(256) void ctx_reduce(const float* __restrict__ part, bf16* __restrict__ ctxT) {
  long i = (long)blockIdx.x * 256 + threadIdx.x;
  int z = (int)(i >> 14);
  int off = (int)(i & 16383);
  float s = 0.f;
#pragma unroll
  for (int c = 0; c < 8; c++) s += part[(((long)z * 8 + c) << 14) + off];
  ctxT[i] = (bf16)s;
}

// ---------------------------------------------------------------------------
extern "C" void kernel_launch(void* const* d_in, const int* in_sizes, int n_in,
                              void* d_out, int out_size, void* d_ws, size_t ws_size,
                              hipStream_t stream) {
  float* outp = (float*)d_out;

  // ---- adaptive arena: pick largest GB in {8,4,2} that fits ws_size ----
  long offH = 0;
  int GB = 0;
  long offLNG, offQ, offK, offV, offATT, offCTXP, offCTXT, offKML, offWT, need;
  for (int gb = 8; gb >= 2; gb >>= 1) {
    long sLN = (long)gb * 4194304;
    offLNG = 67108864L;
    offQ   = offLNG + sLN;
    offK   = offQ + sLN;
    offV   = offK + sLN;
    offATT = offV + sLN;
    offCTXP= offATT + sLN;
    offCTXT= offCTXP + (long)gb * 1572864;
    offKML = offCTXT + (long)gb * 98304;
    offWT  = offKML + (long)gb * 3072;
    need   = offWT + 6553600L;
    if ((size_t)need <= ws_size) { GB = gb; break; }
  }
  if (GB == 0) {
    beacon<<<(out_size + 255) / 256, 256, 0, stream>>>(outp, out_size);
    return;
  }
  const int NG = NBAT / GB;            // groups
  const long GR = (long)GB * SEQ;      // rows per group
  const int NZ = GB * 3;               // linear-attn (batch,head) pairs per group

  const float* x   = (const float*)d_in[0];
  const float* W1  = (const float*)d_in[1];
  const float* b1  = (const float*)d_in[2];
  const float* g1  = (const float*)d_in[3];
  const float* be1 = (const float*)d_in[4];
  const float* Wq  = (const float*)d_in[5];
  const float* Wk  = (const float*)d_in[6];
  const float* Wv  = (const float*)d_in[7];
  const float* Wo  = (const float*)d_in[8];
  const float* bo  = (const float*)d_in[9];
  const float* g2  = (const float*)d_in[10];
  const float* be2 = (const float*)d_in[11];
  const float* Wf1 = (const float*)d_in[12];
  const float* bf1 = (const float*)d_in[13];
  const float* Wf2 = (const float*)d_in[14];
  const float* bf2 = (const float*)d_in[15];
  const float* W2  = (const float*)d_in[16];
  const float* b2  = (const float*)d_in[17];

  char* ws = (char*)d_ws;
  float* h   = (float*)(ws + offH);
  bf16* lnG  = (bf16*)(ws + offLNG);
  bf16* qp   = (bf16*)(ws + offLNG);   // overlays lnG (lnG dead after QKV; qp dead in FFN)
  bf16* qb   = (bf16*)(ws + offQ);
  bf16* kb   = (bf16*)(ws + offK);
  bf16* vb   = (bf16*)(ws + offV);
  bf16* attb = (bf16*)(ws + offATT);
  bf16* ff1g = (bf16*)(ws + offQ);     // overlays q..attn (dead in FFN phase)
  float* ctxp= (float*)(ws + offCTXP);
  bf16* ctxT = (bf16*)(ws + offCTXT);
  float* kml = (float*)(ws + offKML);
  bf16* wt   = (bf16*)(ws + offWT);
  bf16* wqt  = wt + 65536;
  bf16* wot  = wt + 851968;
  bf16* wf1t = wt + 1114112;
  bf16* wf2t = wt + 2162688;
  bf16* w2t  = wt + 3211264;
  const int lOff = NZ * 32 * 128;      // kstats l-plane offset within ctxp

  // ---- all weight transposes (fp32 -> bf16, [Npad][K] K-contiguous) ----
  transpose8<<<dim3(32, 32, 8), 256, 0, stream>>>(W1, Wq, Wk, Wv, Wo, Wf1, Wf2, W2, wt);

  // ---- h = tanh(xpad @ W1 + b1) fp32; pad rows handled in A staging ----
  gemm_bt<<<dim3(4, 256, 1), 256, 0, stream>>>(x, wt, b1, h, nullptr,
      DINP, DINP, DINP, DM, 0, 1, 0, 0, 1, 0, 0);

  // ---- attention, NG groups of GB batches ----
  for (int g = 0; g < NG; g++) {
    float* hg = h + (long)g * GR * DM;
    ln_kernel<<<(int)(GR / 4), 256, 0, stream>>>(hg, g1, be1, lnG);
    // Q,K,V in one z=3 batched launch (outputs land in qb,kb,vb = contiguous)
    gemm_bt<<<dim3(4, (int)(GR / 128), 3), 256, 0, stream>>>(lnG, wqt, nullptr, nullptr, qb,
        DM, DM, DM, DM, 1, 0,
        0L, 262144L, 3, 0L, GR * DM);

    local_attn<<<dim3(2, 32, GB), 256, 0, stream>>>(qb, kb, vb, attb);

    qp_softmax<<<NZ * 1024, 256, 0, stream>>>(qb, qp);
    kstats_part<<<dim3(32, NZ), 128, 0, stream>>>(kb, ctxp, lOff);
    kstats_comb<<<NZ, 128, 0, stream>>>(ctxp, kml, lOff);
    ctx_mfma<<<dim3(8, NZ), 256, 0, stream>>>(kb, vb, kml, ctxp);
    ctx_reduce<<<NZ * 64, 256, 0, stream>>>(ctxp, ctxT);
    gemm_bt<<<dim3(1, 32, NZ), 256, 0, stream>>>(qp, ctxT, nullptr, nullptr, attb + 128,
        128, 128, 128, DM, 1, 0,
        (long)SEQ * 128, 16384L, 3, (long)SEQ * DM, 128L);

    // h += attn @ Wo + bo : 128-tile, block-owned +=
    gemm_bt<<<dim3(4, (int)(GR / 128), 1), 256, 0, stream>>>(attb, wot, bo, hg, nullptr,
        DM, DM, DM, DM, 2, 0, 0, 0, 1, 0, 0);
  }

  // ---- FFN, NG groups ----
  for (int g = 0; g < NG; g++) {
    float* hg = h + (long)g * GR * DM;
    ln_kernel<<<(int)(GR / 4), 256, 0, stream>>>(hg, g2, be2, lnG);
    // FF1: 256-tile with LDS-staged coalesced epilogue
    gemm_bt256<<<dim3(16, (int)(GR / 256), 1), 256, 0, stream>>>(lnG, wf1t, bf1, nullptr, ff1g,
        DM, DM, DM, DFF, 4, 0, 0, 1, 0, 0);
    // h += gelu(ff1) @ Wf2 + bf2 : 128-tile, block-owned +=
    gemm_bt<<<dim3(4, (int)(GR / 128), 1), 256, 0, stream>>>(ff1g, wf2t, bf2, hg, nullptr,
        DFF, DFF, DFF, DM, 2, 0, 0, 0, 1, 0, 0);
  }

  // ---- out = (h @ W2 + b2)[:, :3000, :] -> d_out fp32 (h staged as bf16) ----
  gemm_bt<<<dim3(1, 256, 1), 256, 0, stream>>>(h, w2t, b2, outp, nullptr,
      DM, DM, DM, 64, 5, 2, 0, 0, 1, 0, 0);
}

// Round 15
// 856.637 us; speedup vs baseline: 1.0906x; 1.0906x over previous
//
#include <hip/hip_runtime.h>
#include <hip/hip_bf16.h>
#include <math.h>

// ---------------------------------------------------------------------------
// Linear_Transformer on MI355X (gfx950). fp32 I/O, bf16 MFMA internals,
// fp32 residual stream.
// Round 15: revert to the best measured configuration (round 10, 854us) —
// all GEMM sites on the 128x128 gemm_bt (BK=64 twin half-buffers, async
// global_load_lds staging), GB=8 adaptive arena. The 256-tile arc (r11-r14)
// measured neutral-to-negative at every epilogue variant; deleted.
// ---------------------------------------------------------------------------

typedef __hip_bfloat16 bf16;
typedef __attribute__((ext_vector_type(8))) short short8;   // 8 bf16 (MFMA A/B frag)
typedef __attribute__((ext_vector_type(4))) float floatx4;  // MFMA C/D frag

#define SEQ   4096
#define NBAT  8
#define DM    512
#define DINP  128
#define DFF   2048
#define NREAL 3000
#define CS    40              // ctx_mfma LDS stride (80B, 16B-aligned)

#define MFMA16(a,b,c) __builtin_amdgcn_mfma_f32_16x16x32_bf16((a),(b),(c),0,0,0)

// async global->LDS, 16B per lane, deposits at lds + lane*16
__device__ __forceinline__ void gload_lds16(const void* g, void* l) {
  auto* gp = reinterpret_cast<const __attribute__((address_space(1))) unsigned int*>(
      reinterpret_cast<uintptr_t>(g));
  auto* lp = reinterpret_cast<__attribute__((address_space(3))) unsigned int*>(
      reinterpret_cast<uintptr_t>(l));
  __builtin_amdgcn_global_load_lds(gp, lp, 16, 0, 0);
}

// ---------------------------------------------------------------------------
__global__ __launch_bounds__(256) void beacon(float* __restrict__ out, long n) {
  long i = (long)blockIdx.x * 256 + threadIdx.x;
  if (i < n) out[i] = 10000.f;
}

// ---------------------------------------------------------------------------
// All 8 weight transposes in one launch. Wt[n][k] = n<N ? (bf16)W[k][n] : 0
// ---------------------------------------------------------------------------
__global__ __launch_bounds__(256) void transpose8(
    const float* __restrict__ W1, const float* __restrict__ Wq,
    const float* __restrict__ Wk, const float* __restrict__ Wv,
    const float* __restrict__ Wo, const float* __restrict__ Wf1,
    const float* __restrict__ Wf2, const float* __restrict__ W2,
    bf16* __restrict__ wt) {
  const int Ks[8]   = {128, 512, 512, 512, 512, 512, 2048, 512};
  const int Ns[8]   = {512, 512, 512, 512, 512, 2048, 512, 64};
  const int Nps[8]  = {512, 512, 512, 512, 512, 2048, 512, 128};
  const long Ofs[8] = {0L, 65536L, 327680L, 589824L, 851968L, 1114112L, 2162688L, 3211264L};
  int zi = blockIdx.z;
  int K = Ks[zi], N = Ns[zi], Npad = Nps[zi];
  int k0 = blockIdx.x * 64, n0 = blockIdx.y * 64;
  if (k0 >= K || n0 >= Npad) return;
  const float* W = zi == 0 ? W1 : zi == 1 ? Wq : zi == 2 ? Wk : zi == 3 ? Wv
                 : zi == 4 ? Wo : zi == 5 ? Wf1 : zi == 6 ? Wf2 : W2;
  bf16* Wt = wt + Ofs[zi];
  __shared__ float t[64][65];
  int r = threadIdx.x >> 2, c = (threadIdx.x & 3) * 16;
#pragma unroll
  for (int i = 0; i < 16; i++) {
    int n = n0 + c + i;
    t[r][c + i] = (n < N) ? W[(long)(k0 + r) * N + n] : 0.f;
  }
  __syncthreads();
#pragma unroll
  for (int i = 0; i < 16; i++)
    Wt[(long)(n0 + r) * K + k0 + c + i] = (bf16)t[c + i][r];
}

// ---------------------------------------------------------------------------
__device__ inline uint4 pack8(const float* p) {
  union { bf16 h[8]; uint4 u; } r;
  float4 a = *(const float4*)p;
  float4 b = *(const float4*)(p + 4);
  r.h[0] = (bf16)a.x; r.h[1] = (bf16)a.y; r.h[2] = (bf16)a.z; r.h[3] = (bf16)a.w;
  r.h[4] = (bf16)b.x; r.h[5] = (bf16)b.y; r.h[6] = (bf16)b.z; r.h[7] = (bf16)b.w;
  return r.u;
}

// ---------------------------------------------------------------------------
// Generic MFMA GEMM (round-10, best measured): 128x128 tile.
// AMODE 0: bf16 A async BK=64 twin halves. AMODE 1: fp32 x w/ zero pad rows.
// AMODE 2: fp32 A. EPI: 0 tanh->Cf 1 bf16->Cb 2 Cf+= 4 gelu->Cb 5 remap->Cf
// ---------------------------------------------------------------------------
__global__ __launch_bounds__(256) void gemm_bt(
    const void* __restrict__ Avoid, const bf16* __restrict__ Bt,
    const float* __restrict__ bias, float* __restrict__ Cf, bf16* __restrict__ Cb,
    int K, int lda, int ldb, int ldc, int EPI, int AMODE,
    long aBatch, long bBatch, int zdiv, long cOuter, long cInner) {
  __shared__ __align__(16) bf16 As0[128 * 32];
  __shared__ __align__(16) bf16 As1[128 * 32];
  __shared__ __align__(16) bf16 Bs0[128 * 32];
  __shared__ __align__(16) bf16 Bs1[128 * 32];
  const int tid = threadIdx.x;
  const int bz = blockIdx.z;
  Bt += (long)bz * bBatch;
  const long cOff = (long)(bz / zdiv) * cOuter + (long)(bz % zdiv) * cInner;
  const int row0 = blockIdx.y * 128;
  const int col0 = blockIdx.x * 128;
  const int lane = tid & 63, wid = tid >> 6;
  const int wm = (wid & 1) * 64, wn = (wid >> 1) * 64;
  const int lr = lane & 15, lk = (lane >> 4) * 8;

  floatx4 acc[4][4];
#pragma unroll
  for (int i = 0; i < 4; i++)
#pragma unroll
    for (int j = 0; j < 4; j++) acc[i][j] = {0.f, 0.f, 0.f, 0.f};

  if (AMODE == 0) {
    const bf16* A = (const bf16*)Avoid + (long)bz * aBatch;
    const bf16* pAa = A + (long)(row0 + wid * 16 + (lane >> 2)) * lda + (lane & 3) * 8;
    const bf16* pBa = Bt + (long)(col0 + wid * 16 + (lane >> 2)) * ldb + (lane & 3) * 8;
    bf16* ldsA0 = &As0[wid * 16 * 32];
    bf16* ldsA1 = &As1[wid * 16 * 32];
    bf16* ldsB0 = &Bs0[wid * 16 * 32];
    bf16* ldsB1 = &Bs1[wid * 16 * 32];
    const long a64 = (long)64 * lda, b64 = (long)64 * ldb;
    for (int k0 = 0; k0 < K; k0 += 64) {
      __syncthreads();
      gload_lds16(pAa, ldsA0);
      gload_lds16(pAa + a64, ldsA0 + 64 * 32);
      gload_lds16(pAa + 32, ldsA1);
      gload_lds16(pAa + a64 + 32, ldsA1 + 64 * 32);
      gload_lds16(pBa, ldsB0);
      gload_lds16(pBa + b64, ldsB0 + 64 * 32);
      gload_lds16(pBa + 32, ldsB1);
      gload_lds16(pBa + b64 + 32, ldsB1 + 64 * 32);
      pAa += 64; pBa += 64;
      __syncthreads();
      short8 af[4], bfr[4];
#pragma unroll
      for (int mt = 0; mt < 4; mt++) af[mt] = *(const short8*)(&As0[(wm + mt * 16 + lr) * 32 + lk]);
#pragma unroll
      for (int nt = 0; nt < 4; nt++) bfr[nt] = *(const short8*)(&Bs0[(wn + nt * 16 + lr) * 32 + lk]);
#pragma unroll
      for (int mt = 0; mt < 4; mt++)
#pragma unroll
        for (int nt = 0; nt < 4; nt++)
          acc[mt][nt] = MFMA16(af[mt], bfr[nt], acc[mt][nt]);
#pragma unroll
      for (int mt = 0; mt < 4; mt++) af[mt] = *(const short8*)(&As1[(wm + mt * 16 + lr) * 32 + lk]);
#pragma unroll
      for (int nt = 0; nt < 4; nt++) bfr[nt] = *(const short8*)(&Bs1[(wn + nt * 16 + lr) * 32 + lk]);
#pragma unroll
      for (int mt = 0; mt < 4; mt++)
#pragma unroll
        for (int nt = 0; nt < 4; nt++)
          acc[mt][nt] = MFMA16(af[mt], bfr[nt], acc[mt][nt]);
    }
  } else {
    const float* Af = (const float*)Avoid;
    const int srow = tid >> 2;
    const int skcol = (tid & 3) * 8;
    const long r0 = row0 + srow, r1 = r0 + 64;
    const bf16* pB = Bt + (long)(col0 + srow) * ldb + skcol;
    const int ldsOff = srow * 32 + skcol;
    const float* pF0; const float* pF1;
    bool v0 = true, v1 = true;
    if (AMODE == 1) {
      int t0 = (int)(r0 & (SEQ - 1)), t1 = (int)(r1 & (SEQ - 1));
      v0 = t0 < NREAL; v1 = t1 < NREAL;
      if (!v0) t0 = 0;
      if (!v1) t1 = 0;
      pF0 = Af + ((r0 >> 12) * NREAL + t0) * DINP + skcol;
      pF1 = Af + ((r1 >> 12) * NREAL + t1) * DINP + skcol;
    } else {
      pF0 = Af + r0 * lda + skcol;
      pF1 = Af + r1 * lda + skcol;
    }
    for (int k0 = 0; k0 < K; k0 += 32) {
      uint4 b0 = *(const uint4*)(pB);
      uint4 b1 = *(const uint4*)(pB + (long)64 * ldb);
      pB += 32;
      uint4 a0 = {0, 0, 0, 0}, a1 = {0, 0, 0, 0};
      if (v0) a0 = pack8(pF0);
      if (v1) a1 = pack8(pF1);
      pF0 += 32; pF1 += 32;
      __syncthreads();
      *(uint4*)(&As0[ldsOff]) = a0;
      *(uint4*)(&As0[ldsOff + 64 * 32]) = a1;
      *(uint4*)(&Bs0[ldsOff]) = b0;
      *(uint4*)(&Bs0[ldsOff + 64 * 32]) = b1;
      __syncthreads();
      short8 af[4], bfr[4];
#pragma unroll
      for (int mt = 0; mt < 4; mt++) af[mt] = *(const short8*)(&As0[(wm + mt * 16 + lr) * 32 + lk]);
#pragma unroll
      for (int nt = 0; nt < 4; nt++) bfr[nt] = *(const short8*)(&Bs0[(wn + nt * 16 + lr) * 32 + lk]);
#pragma unroll
      for (int mt = 0; mt < 4; mt++)
#pragma unroll
        for (int nt = 0; nt < 4; nt++)
          acc[mt][nt] = MFMA16(af[mt], bfr[nt], acc[mt][nt]);
    }
  }

#pragma unroll
  for (int nt = 0; nt < 4; nt++) {
    int c = col0 + wn + nt * 16 + lr;
    float bv = 0.f;
    if (bias) {
      if (EPI == 5) { if (c < 64) bv = bias[c]; }
      else bv = bias[c];
    }
#pragma unroll
    for (int mt = 0; mt < 4; mt++) {
      long rb = row0 + wm + mt * 16 + (lane >> 4) * 4;
#pragma unroll
      for (int reg = 0; reg < 4; reg++) {
        float v = acc[mt][nt][reg] + bv;
        long ri = rb + reg;
        long idx = cOff + ri * (long)ldc + c;
        if (EPI == 0) Cf[idx] = tanhf(v);
        else if (EPI == 1) Cb[idx] = (bf16)v;
        else if (EPI == 2) Cf[idx] += v;
        else if (EPI == 4) { float g = 0.5f * v * (1.f + erff(v * 0.70710678118654752f)); Cb[idx] = (bf16)g; }
        else if (EPI == 5) {
          int bb = (int)(ri >> 12); int tt = (int)(ri & (SEQ - 1));
          if (tt < NREAL && c < 64) Cf[((long)bb * NREAL + tt) * 64 + c] = v;
        }
      }
    }
  }
}

// ---------------------------------------------------------------------------
// LayerNorm over 512 fp32 -> bf16. One wave per row, 4 rows per block.
// ---------------------------------------------------------------------------
__global__ __launch_bounds__(256) void ln_kernel(const float* __restrict__ h,
                                                 const float* __restrict__ g,
                                                 const float* __restrict__ bta,
                                                 bf16* __restrict__ out) {
  int wid = threadIdx.x >> 6, lane = threadIdx.x & 63;
  long row = (long)blockIdx.x * 4 + wid;
  const float* src = h + row * DM + lane * 8;
  float4 a = *(const float4*)(src);
  float4 b = *(const float4*)(src + 4);
  float x[8] = {a.x, a.y, a.z, a.w, b.x, b.y, b.z, b.w};
  float s = 0.f, sq = 0.f;
#pragma unroll
  for (int i = 0; i < 8; i++) { s += x[i]; sq += x[i] * x[i]; }
#pragma unroll
  for (int m = 32; m >= 1; m >>= 1) { s += __shfl_xor(s, m, 64); sq += __shfl_xor(sq, m, 64); }
  float mu = s * (1.f / DM);
  float var = sq * (1.f / DM) - mu * mu;
  float rstd = rsqrtf(var + 1e-5f);
  const float* gp = g + lane * 8;
  const float* bp = bta + lane * 8;
  bf16* dst = out + row * DM + lane * 8;
#pragma unroll
  for (int i = 0; i < 8; i++)
    dst[i] = (bf16)((x[i] - mu) * rstd * gp[i] + bp[i]);
}

// ---------------------------------------------------------------------------
// Local attention, head 0. Grid (2 halves, 32 windows, GB batches).
// ---------------------------------------------------------------------------
__global__ __launch_bounds__(256) void local_attn(const bf16* __restrict__ q,
                                                  const bf16* __restrict__ k,
                                                  const bf16* __restrict__ v,
                                                  bf16* __restrict__ att) {
  int half = blockIdx.x, w = blockIdx.y, b = blockIdx.z;
  int tid = threadIdx.x, wid = tid >> 6, lane = tid & 63;
  int lr = lane & 15, lq4 = lane >> 4;
  __shared__ __align__(16) bf16 Ks[32 * 128];   // [j][d]
  __shared__ __align__(16) bf16 Vts[128 * 32];  // [d][j]
  __shared__ __align__(16) bf16 Ps[4][16 * 32]; // per-wave P scratch

  int t0 = w * 128 + half * 64 + wid * 16;
  long qbase = ((long)b * SEQ + t0 + lr) * DM;
  short8 qf[4];
#pragma unroll
  for (int ks = 0; ks < 4; ks++) qf[ks] = *(const short8*)(q + qbase + ks * 32 + lq4 * 8);

  floatx4 Oacc[8];
#pragma unroll
  for (int i = 0; i < 8; i++) Oacc[i] = {0.f, 0.f, 0.f, 0.f};
  float rs[4] = {0.f, 0.f, 0.f, 0.f};

  int keystart = w * 128 - 128;
  for (int ch = 0; ch < 12; ch++) {
    int kb = keystart + ch * 32;
    if (kb < 0 || kb >= SEQ) continue;  // uniform per block
    {
      int j = tid >> 3, d = (tid & 7) * 16;
      const bf16* ksrc = k + ((long)b * SEQ + kb + j) * DM + d;
      *(uint4*)(&Ks[j * 128 + d]) = *(const uint4*)(ksrc);
      *(uint4*)(&Ks[j * 128 + d + 8]) = *(const uint4*)(ksrc + 8);
      const bf16* vsrc = v + ((long)b * SEQ + kb + j) * DM + d;
#pragma unroll
      for (int e = 0; e < 16; e++) Vts[(d + e) * 32 + j] = vsrc[e];
    }
    __syncthreads();
    floatx4 s0 = {0.f, 0.f, 0.f, 0.f}, s1 = {0.f, 0.f, 0.f, 0.f};
#pragma unroll
    for (int ks = 0; ks < 4; ks++) {
      short8 kf0 = *(const short8*)(&Ks[(0 + lr) * 128 + ks * 32 + lq4 * 8]);
      short8 kf1 = *(const short8*)(&Ks[(16 + lr) * 128 + ks * 32 + lq4 * 8]);
      s0 = MFMA16(qf[ks], kf0, s0);
      s1 = MFMA16(qf[ks], kf1, s1);
    }
#pragma unroll
    for (int reg = 0; reg < 4; reg++) {
      float e0 = __expf(s0[reg] * 0.08838834764831845f);
      float e1 = __expf(s1[reg] * 0.08838834764831845f);
      rs[reg] += e0 + e1;
      Ps[wid][(lq4 * 4 + reg) * 32 + lr] = (bf16)e0;
      Ps[wid][(lq4 * 4 + reg) * 32 + 16 + lr] = (bf16)e1;
    }
    __syncthreads();
    short8 pf = *(const short8*)(&Ps[wid][lr * 32 + lq4 * 8]);
#pragma unroll
    for (int nt = 0; nt < 8; nt++) {
      short8 vf = *(const short8*)(&Vts[(nt * 16 + lr) * 32 + lq4 * 8]);
      Oacc[nt] = MFMA16(pf, vf, Oacc[nt]);
    }
    __syncthreads();
  }
#pragma unroll
  for (int m = 1; m < 16; m <<= 1)
#pragma unroll
    for (int reg = 0; reg < 4; reg++) rs[reg] += __shfl_xor(rs[reg], m, 64);
  long obase = ((long)b * SEQ + t0 + lq4 * 4) * DM;
#pragma unroll
  for (int nt = 0; nt < 8; nt++)
#pragma unroll
    for (int reg = 0; reg < 4; reg++)
      att[obase + (long)reg * DM + nt * 16 + lr] = (bf16)(Oacc[nt][reg] / rs[reg]);
}

// ---------------------------------------------------------------------------
// Linear-attn q-softmax: qp[z][t][128] = softmax(q_head)*d^-0.5, z=lb*3+h2
// ---------------------------------------------------------------------------
__global__ __launch_bounds__(256) void qp_softmax(const bf16* __restrict__ q, bf16* __restrict__ qp) {
  int wid = threadIdx.x >> 6, lane = threadIdx.x & 63;
  long task = (long)blockIdx.x * 4 + wid;
  int tt = (int)(task & (SEQ - 1));
  int z6 = (int)(task >> 12);
  int lb = z6 / 3, h2 = z6 % 3;
  const bf16* src = q + ((long)lb * SEQ + tt) * DM + (h2 + 1) * 128 + lane * 2;
  float x0 = (float)src[0], x1 = (float)src[1];
  float m = fmaxf(x0, x1);
#pragma unroll
  for (int s = 32; s >= 1; s >>= 1) m = fmaxf(m, __shfl_xor(m, s, 64));
  float e0 = __expf(x0 - m), e1 = __expf(x1 - m);
  float sm = e0 + e1;
#pragma unroll
  for (int s = 32; s >= 1; s >>= 1) sm += __shfl_xor(sm, s, 64);
  float inv = 0.08838834764831845f / sm;
  bf16* dst = qp + task * 128 + lane * 2;
  dst[0] = (bf16)(e0 * inv);
  dst[1] = (bf16)(e1 * inv);
}

// ---------------------------------------------------------------------------
// k column stats, phase 1: per-(z, 128-row chunk) column max and exp-sum.
// ---------------------------------------------------------------------------
__global__ __launch_bounds__(128) void kstats_part(const bf16* __restrict__ k,
                                                   float* __restrict__ part, int lOff) {
  int chunk = blockIdx.x, z = blockIdx.y;
  int lb = z / 3, h2 = z % 3, ch = (h2 + 1) * 128;
  int d = threadIdx.x;
  const bf16* base = k + ((long)lb * SEQ + chunk * 128) * DM + ch + d;
  float m = -1e30f;
#pragma unroll 4
  for (int t = 0; t < 128; t++) m = fmaxf(m, (float)base[(long)t * DM]);
  float l = 0.f;
#pragma unroll 4
  for (int t = 0; t < 128; t++) l += __expf((float)base[(long)t * DM] - m);
  int idx = (z * 32 + chunk) * 128 + d;
  part[idx] = m;
  part[lOff + idx] = l;
}

// phase 2: combine 32 chunk stats -> kml[z*256+d]=M, +128=L
__global__ __launch_bounds__(128) void kstats_comb(const float* __restrict__ part,
                                                   float* __restrict__ kml, int lOff) {
  int z = blockIdx.x, d = threadIdx.x;
  float M = -1e30f;
#pragma unroll 4
  for (int c = 0; c < 32; c++) M = fmaxf(M, part[(z * 32 + c) * 128 + d]);
  float L = 0.f;
#pragma unroll 4
  for (int c = 0; c < 32; c++) {
    int i = (z * 32 + c) * 128 + d;
    L += part[lOff + i] * __expf(part[i] - M);
  }
  kml[z * 256 + d] = M;
  kml[z * 256 + 128 + d] = L;
}

// ---------------------------------------------------------------------------
// ctx via MFMA: part[z][chunk][e*128+d] = sum_{t in 512-chunk} v[t][e]*k'[t][d]
// ---------------------------------------------------------------------------
__global__ __launch_bounds__(256) void ctx_mfma(const bf16* __restrict__ k,
                                                const bf16* __restrict__ v,
                                                const float* __restrict__ kml,
                                                float* __restrict__ part) {
  int chunk = blockIdx.x, z = blockIdx.y;
  int lb = z / 3, h2 = z % 3, ch = (h2 + 1) * 128;
  int tid = threadIdx.x, lane = tid & 63, wid = tid >> 6;
  const int wm = (wid & 1) * 64, wn = (wid >> 1) * 64;
  const int lr = lane & 15, lk = (lane >> 4) * 8;
  __shared__ float ml2[128];
  __shared__ __align__(16) bf16 Vt[128 * CS];
  __shared__ __align__(16) bf16 Kt[128 * CS];
  if (tid < 128)
    ml2[tid] = kml[z * 256 + tid] + logf(kml[z * 256 + 128 + tid]);

  int j = tid >> 3, d0 = (tid & 7) * 16;
  const bf16* vsrc = v + ((long)lb * SEQ + chunk * 512 + j) * DM + ch + d0;
  const bf16* ksrc = k + ((long)lb * SEQ + chunk * 512 + j) * DM + ch + d0;

  floatx4 acc[4][4];
#pragma unroll
  for (int i = 0; i < 4; i++)
#pragma unroll
    for (int jj = 0; jj < 4; jj++) acc[i][jj] = {0.f, 0.f, 0.f, 0.f};

  for (int s = 0; s < 16; s++) {
    union { bf16 h[16]; uint4 u[2]; } va, ka;
    va.u[0] = *(const uint4*)(vsrc); va.u[1] = *(const uint4*)(vsrc + 8);
    ka.u[0] = *(const uint4*)(ksrc); ka.u[1] = *(const uint4*)(ksrc + 8);
    vsrc += (long)32 * DM; ksrc += (long)32 * DM;
    __syncthreads();
#pragma unroll
    for (int e = 0; e < 16; e++) {
      Vt[(d0 + e) * CS + j] = va.h[e];
      Kt[(d0 + e) * CS + j] = (bf16)__expf((float)ka.h[e] - ml2[d0 + e]);
    }
    __syncthreads();
    short8 af[4], bfr[4];
#pragma unroll
    for (int mt = 0; mt < 4; mt++) af[mt] = *(const short8*)(&Vt[(wm + mt * 16 + lr) * CS + lk]);
#pragma unroll
    for (int nt = 0; nt < 4; nt++) bfr[nt] = *(const short8*)(&Kt[(wn + nt * 16 + lr) * CS + lk]);
#pragma unroll
    for (int mt = 0; mt < 4; mt++)
#pragma unroll
      for (int nt = 0; nt < 4; nt++)
        acc[mt][nt] = MFMA16(af[mt], bfr[nt], acc[mt][nt]);
  }

  float* dst = part + ((long)z * 8 + chunk) * 16384;
#pragma unroll
  for (int nt = 0; nt < 4; nt++) {
    int c = wn + nt * 16 + lr;
#pragma unroll
    for (int mt = 0; mt < 4; mt++) {
      int rb = wm + mt * 16 + (lane >> 4) * 4;
#pragma unroll
      for (int reg = 0; reg < 4; reg++)
        dst[(rb + reg) * 128 + c] = acc[mt][nt][reg];
    }
  }
}

__global__ __launch_bounds__(256) void ctx_reduce(const float* __restrict__ part, bf16* __restrict__ ctxT) {
  long i = (long)blockIdx.x * 256 + threadIdx.x;
  int z = (int)(i >> 14);
  int off = (int)(i & 16383);
  float s = 0.f;
#pragma unroll
  for (int c = 0; c < 8; c++) s += part[(((long)z * 8 + c) << 14) + off];
  ctxT[i] = (bf16)s;
}

// ---------------------------------------------------------------------------
extern "C" void kernel_launch(void* const* d_in, const int* in_sizes, int n_in,
                              void* d_out, int out_size, void* d_ws, size_t ws_size,
                              hipStream_t stream) {
  float* outp = (float*)d_out;

  // ---- adaptive arena: pick largest GB in {8,4,2} that fits ws_size ----
  long offH = 0;
  int GB = 0;
  long offLNG, offQ, offK, offV, offATT, offCTXP, offCTXT, offKML, offWT, need;
  for (int gb = 8; gb >= 2; gb >>= 1) {
    long sLN = (long)gb * 4194304;
    offLNG = 67108864L;
    offQ   = offLNG + sLN;
    offK   = offQ + sLN;
    offV   = offK + sLN;
    offATT = offV + sLN;
    offCTXP= offATT + sLN;
    offCTXT= offCTXP + (long)gb * 1572864;
    offKML = offCTXT + (long)gb * 98304;
    offWT  = offKML + (long)gb * 3072;
    need   = offWT + 6553600L;
    if ((size_t)need <= ws_size) { GB = gb; break; }
  }
  if (GB == 0) {
    beacon<<<(out_size + 255) / 256, 256, 0, stream>>>(outp, out_size);
    return;
  }
  const int NG = NBAT / GB;            // groups
  const long GR = (long)GB * SEQ;      // rows per group
  const int NZ = GB * 3;               // linear-attn (batch,head) pairs per group

  const float* x   = (const float*)d_in[0];
  const float* W1  = (const float*)d_in[1];
  const float* b1  = (const float*)d_in[2];
  const float* g1  = (const float*)d_in[3];
  const float* be1 = (const float*)d_in[4];
  const float* Wq  = (const float*)d_in[5];
  const float* Wk  = (const float*)d_in[6];
  const float* Wv  = (const float*)d_in[7];
  const float* Wo  = (const float*)d_in[8];
  const float* bo  = (const float*)d_in[9];
  const float* g2  = (const float*)d_in[10];
  const float* be2 = (const float*)d_in[11];
  const float* Wf1 = (const float*)d_in[12];
  const float* bf1 = (const float*)d_in[13];
  const float* Wf2 = (const float*)d_in[14];
  const float* bf2 = (const float*)d_in[15];
  const float* W2  = (const float*)d_in[16];
  const float* b2  = (const float*)d_in[17];

  char* ws = (char*)d_ws;
  float* h   = (float*)(ws + offH);
  bf16* lnG  = (bf16*)(ws + offLNG);
  bf16* qp   = (bf16*)(ws + offLNG);   // overlays lnG (lnG dead after QKV; qp dead in FFN)
  bf16* qb   = (bf16*)(ws + offQ);
  bf16* kb   = (bf16*)(ws + offK);
  bf16* vb   = (bf16*)(ws + offV);
  bf16* attb = (bf16*)(ws + offATT);
  bf16* ff1g = (bf16*)(ws + offQ);     // overlays q..attn (dead in FFN phase)
  float* ctxp= (float*)(ws + offCTXP);
  bf16* ctxT = (bf16*)(ws + offCTXT);
  float* kml = (float*)(ws + offKML);
  bf16* wt   = (bf16*)(ws + offWT);
  bf16* wqt  = wt + 65536;
  bf16* wot  = wt + 851968;
  bf16* wf1t = wt + 1114112;
  bf16* wf2t = wt + 2162688;
  bf16* w2t  = wt + 3211264;
  const int lOff = NZ * 32 * 128;      // kstats l-plane offset within ctxp

  // ---- all weight transposes (fp32 -> bf16, [Npad][K] K-contiguous) ----
  transpose8<<<dim3(32, 32, 8), 256, 0, stream>>>(W1, Wq, Wk, Wv, Wo, Wf1, Wf2, W2, wt);

  // ---- h = tanh(xpad @ W1 + b1) fp32; pad rows handled in A staging ----
  gemm_bt<<<dim3(4, 256, 1), 256, 0, stream>>>(x, wt, b1, h, nullptr,
      DINP, DINP, DINP, DM, 0, 1, 0, 0, 1, 0, 0);

  // ---- attention, NG groups of GB batches ----
  for (int g = 0; g < NG; g++) {
    float* hg = h + (long)g * GR * DM;
    ln_kernel<<<(int)(GR / 4), 256, 0, stream>>>(hg, g1, be1, lnG);
    // Q,K,V in one z=3 batched launch (outputs land in qb,kb,vb = contiguous)
    gemm_bt<<<dim3(4, (int)(GR / 128), 3), 256, 0, stream>>>(lnG, wqt, nullptr, nullptr, qb,
        DM, DM, DM, DM, 1, 0,
        0L, 262144L, 3, 0L, GR * DM);

    local_attn<<<dim3(2, 32, GB), 256, 0, stream>>>(qb, kb, vb, attb);

    qp_softmax<<<NZ * 1024, 256, 0, stream>>>(qb, qp);
    kstats_part<<<dim3(32, NZ), 128, 0, stream>>>(kb, ctxp, lOff);
    kstats_comb<<<NZ, 128, 0, stream>>>(ctxp, kml, lOff);
    ctx_mfma<<<dim3(8, NZ), 256, 0, stream>>>(kb, vb, kml, ctxp);
    ctx_reduce<<<NZ * 64, 256, 0, stream>>>(ctxp, ctxT);
    gemm_bt<<<dim3(1, 32, NZ), 256, 0, stream>>>(qp, ctxT, nullptr, nullptr, attb + 128,
        128, 128, 128, DM, 1, 0,
        (long)SEQ * 128, 16384L, 3, (long)SEQ * DM, 128L);

    // h += attn @ Wo + bo : 128-tile, block-owned +=
    gemm_bt<<<dim3(4, (int)(GR / 128), 1), 256, 0, stream>>>(attb, wot, bo, hg, nullptr,
        DM, DM, DM, DM, 2, 0, 0, 0, 1, 0, 0);
  }

  // ---- FFN, NG groups ----
  for (int g = 0; g < NG; g++) {
    float* hg = h + (long)g * GR * DM;
    ln_kernel<<<(int)(GR / 4), 256, 0, stream>>>(hg, g2, be2, lnG);
    gemm_bt<<<dim3(16, (int)(GR / 128), 1), 256, 0, stream>>>(lnG, wf1t, bf1, nullptr, ff1g,
        DM, DM, DM, DFF, 4, 0, 0, 0, 1, 0, 0);
    // h += gelu(ff1) @ Wf2 + bf2 : 128-tile, block-owned +=
    gemm_bt<<<dim3(4, (int)(GR / 128), 1), 256, 0, stream>>>(ff1g, wf2t, bf2, hg, nullptr,
        DFF, DFF, DFF, DM, 2, 0, 0, 0, 1, 0, 0);
  }

  // ---- out = (h @ W2 + b2)[:, :3000, :] -> d_out fp32 (h staged as bf16) ----
  gemm_bt<<<dim3(1, 256, 1), 256, 0, stream>>>(h, w2t, b2, outp, nullptr,
      DM, DM, DM, 64, 5, 2, 0, 0, 1, 0, 0);
}